// Round 9
// baseline (578.825 us; speedup 1.0000x reference)
//
#include <hip/hip_runtime.h>
#include <math.h>

#define NYg 1024
#define NXg 1024
#define W   1024
#define NSTEPS 64
#define GRID_N (NYg * W)
#define NB    512                     // blocks; block b owns rows 2b, 2b+1

// ---- ctrl (dword offsets in d_ws) ----
#define NSLOT 16                      // max-reduction slots per step
#define SLOT_STRIDE 32
#define SLOT_GROUP  (NSLOT * SLOT_STRIDE)     // 512 dwords
#define NSLOTG      (NSTEPS + 1)
#define WS_CNT  (NSLOTG * SLOT_GROUP)         // 16 group counters * 32 dwords
#define WS_NBF  (WS_CNT + NSLOT * 32)         // NB neighbor flags * 32 dwords
#define WS_CTRL_END (WS_NBF + NB * 32)
#define WS_GRIDS 65536                // float offset where exchange arrays begin (256 KB)

constexpr float DXf   = 50.0f;
constexpr float DYf   = 50.0f;
constexpr float TTOTf = 32.0f;
constexpr float DTMAXf= 0.5f;
constexpr float EPSf  = 1e-10f;
constexpr float TFREQ = 5.0f;
constexpr float LAPSE = 0.0065f;
constexpr float MELTF = 0.5f;
constexpr double RHOG = 910.0 * 9.81;
constexpr float  CDf  = (float)(1e-17 * RHOG * RHOG * RHOG);

// memory-side (coherence-point) accessors — bypass non-coherent per-XCD L2s
__device__ __forceinline__ float scloadf(const float* p) {
    return __hip_atomic_load(p, __ATOMIC_RELAXED, __HIP_MEMORY_SCOPE_SYSTEM);
}
__device__ __forceinline__ void scstoref(float* p, float v) {
    __hip_atomic_store(p, v, __ATOMIC_RELAXED, __HIP_MEMORY_SCOPE_SYSTEM);
}
__device__ __forceinline__ unsigned scloadu(const unsigned* p) {
    return __hip_atomic_load(p, __ATOMIC_RELAXED, __HIP_MEMORY_SCOPE_SYSTEM);
}

// backoff poll helper: s_sleep arg must be a compile-time constant
__device__ __forceinline__ void poll_backoff(int& sp) {
    if (sp < 32) { __builtin_amdgcn_s_sleep(1); ++sp; }
    else           __builtin_amdgcn_s_sleep(8);
}

// diffusivity on one staggered cell — expression verbatim from the bit-exact R2 kernel
__device__ __forceinline__ float dfunc(float h00, float h01, float h10, float h11,
                                       float z00, float z01, float z10, float z11)
{
    float havg = 0.25f * (h00 + h11 + h01 + h10);
    float sx = ((z01 - z00) + (z11 - z10)) * (0.5f / DXf);
    float sy = ((z10 - z00) + (z11 - z01)) * (0.5f / DYf);
    float sn = sqrtf(sx * sx + sy * sy + EPSf);
    float h2 = havg * havg;
    float h4 = h2 * h2;
    return CDf * (h4 * havg) * (sn * sn) + EPSf;
}

// ---------------- init: zero ctrl, seed slot group 0 with EPS (D(0)==EPS exactly) ----
__global__ __launch_bounds__(256) void k_init(unsigned* __restrict__ ctrl)
{
    int idx = blockIdx.x * blockDim.x + threadIdx.x;
    int stride = gridDim.x * blockDim.x;
    for (int i = idx; i < WS_CTRL_END; i += stride) {
        unsigned v = 0u;
        if (i < SLOT_GROUP && (i & (SLOT_STRIDE - 1)) == 0) v = __float_as_uint(EPSf);
        ctrl[i] = v;
    }
}

// ---------------- persistent kernel: 512 blocks x 2 rows, 2 blocks/CU ----------------
__global__ __launch_bounds__(1024, 8) void k_run(
    float* __restrict__ EZ0, float* __restrict__ EZ1,
    float* __restrict__ ED0, float* __restrict__ ED1,
    const float* __restrict__ ztopo, const float* __restrict__ precip,
    const float* __restrict__ mask, const float* __restrict__ tma,
    const float* __restrict__ tmj, unsigned* __restrict__ ctrl,
    float* __restrict__ Hout)
{
    __shared__ float sZ[5][W];    // z rows r0-1 .. r0+3
    __shared__ float sHm[3][W];   // h rows r0 .. r0+2
    __shared__ float sD[4][W];    // staggered D rows r0-1 .. r0+2
    __shared__ unsigned su[NSLOT];
    __shared__ float smax16[16];

    unsigned* slots = ctrl;
    unsigned* cnt   = ctrl + WS_CNT;
    unsigned* nbf   = ctrl + WS_NBF;

    const int c   = threadIdx.x;          // column 0..1023
    const int b   = blockIdx.x;           // owns rows 2b, 2b+1 (+1 redundant: 2b+2)
    const int r0  = b * 2;
    const int grp = b & (NSLOT - 1);
    const int lane = c & 63, wid = c >> 6;
    const bool hasA = (b > 0), hasB = (b < NB - 1);

    const float TMA = tma[0], TMJ = tmj[0];

    float smbr[3], ztr[3], hN[3];

    // ---- pre-loop: state(0) into LDS; D(0)=EPS; smb(0), ztopo into registers ----
    #pragma unroll
    for (int q = 0; q < 5; ++q) {
        int r = r0 - 1 + q;
        sZ[q][c] = (r >= 0 && r < NYg) ? ztopo[r * W + c] : 0.0f;
    }
    #pragma unroll
    for (int q = 0; q < 3; ++q) sHm[q][c] = 0.0f;
    #pragma unroll
    for (int q = 0; q < 4; ++q) sD[q][c] = EPSf;
    #pragma unroll
    for (int rr = 0; rr < 3; ++rr) {
        int r = r0 + rr;
        if (r < NYg) {
            float z = ztopo[r * W + c];
            ztr[rr] = z;
            float t_ma = TMA - LAPSE * z;
            float t_mj = TMJ - LAPSE * z;
            float acc  = (t_ma < 0.0f) ? precip[r * W + c] : 0.0f;
            float abl  = MELTF * fmaxf(t_mj, 0.0f);
            smbr[rr] = (acc - abl) * mask[r * W + c];
        } else { ztr[rr] = 0.0f; smbr[rr] = 0.0f; }
    }
    __syncthreads();

    float t = 0.0f, tl = 0.0f;

    for (int s = 0; s < NSTEPS; ++s) {
        const float* EZr = (s & 1) ? EZ1 : EZ0;   // state s halos
        float*       EZw = (s & 1) ? EZ0 : EZ1;   // state s+1 halos
        const float* EDr = (s & 1) ? ED1 : ED0;
        float*       EDw = (s & 1) ? ED0 : ED1;

        // ---- A: neighbor-flag wait + halo import ----
        if (s > 0) {
            if (c == 0 && hasA) {
                int sp = 0;
                while (scloadu(&nbf[(b - 1) * 32]) < (unsigned)s) poll_backoff(sp);
            }
            if (c == 64 && hasB) {
                int sp = 0;
                while (scloadu(&nbf[(b + 1) * 32]) < (unsigned)s) poll_backoff(sp);
            }
            __syncthreads();
            if (hasA) { sZ[0][c] = scloadf(EZr + (r0 - 1) * W + c);          // z row r0-1
                        if (c <= NXg - 2) sD[0][c] = scloadf(EDr + (r0 - 1) * W + c); }
            if (hasB) { sZ[4][c] = scloadf(EZr + (r0 + 3) * W + c);          // z row r0+3
                        if (c <= NXg - 2) sD[3][c] = scloadf(EDr + (r0 + 2) * W + c); }
            __syncthreads();
        }

        // ---- C1: dHdt (dt-independent) into registers ----
        float dh[3], hOld[3], zOld[3];
        bool inter[3];
        #pragma unroll
        for (int rr = 0; rr < 3; ++rr) {
            int r = r0 + rr;
            float zc = 0.0f, hc = 0.0f, d = 0.0f;
            bool iv = false;
            if (r < NYg) {
                zc = sZ[rr + 1][c];
                hc = sHm[rr][c];
                iv = (r >= 1 && r <= NYg - 2 && c >= 1 && c <= NXg - 2);
                if (iv) {
                    float zl = sZ[rr + 1][c - 1], zr = sZ[rr + 1][c + 1];
                    float zt = sZ[rr][c],         zb = sZ[rr + 2][c];
                    float d00 = sD[rr][c - 1],     d01 = sD[rr][c];
                    float d10 = sD[rr + 1][c - 1], d11 = sD[rr + 1][c];
                    float qxR = -0.5f * (d01 + d11) * (zr - zc) * (1.0f / DXf);
                    float qxL = -0.5f * (d00 + d10) * (zc - zl) * (1.0f / DXf);
                    float qyB = -0.5f * (d10 + d11) * (zb - zc) * (1.0f / DYf);
                    float qyT = -0.5f * (d00 + d01) * (zc - zt) * (1.0f / DYf);
                    d = -((qxR - qxL) * (1.0f / DXf) + (qyB - qyT) * (1.0f / DYf));
                }
            }
            dh[rr] = d; hOld[rr] = hc; zOld[rr] = zc; inter[rr] = iv;
        }

        // ---- W: deferred global-max wait (monotone counters; 32 blocks/group) ----
        if (c < NSLOT) {
            unsigned tgt = 32u * (unsigned)s;
            int sp = 0;
            while (scloadu(&cnt[c * 32]) < tgt) poll_backoff(sp);
            su[c] = scloadu(&slots[s * SLOT_GROUP + c * SLOT_STRIDE]);
        }
        __syncthreads();   // also: all C1 LDS reads complete before E writes

        unsigned mb = su[0];
        #pragma unroll
        for (int q = 1; q < NSLOT; ++q) mb = max(mb, su[q]);
        float mD = __uint_as_float(mb);
        float dt = fminf(2500.0f / (2.7f * mD), DTMAXf);
        if (!(t < TTOTf)) dt = 0.0f;
        float nt  = t + dt;
        bool  upd = (nt - tl) >= TFREQ;

        // ---- C2+E: finalize h/z, LDS writeback, z halo export, smb refresh ----
        #pragma unroll
        for (int rr = 0; rr < 3; ++rr) {
            int r = r0 + rr;
            float h, z;
            if (r >= NYg)        { h = 0.0f; z = 0.0f; }
            else if (inter[rr])  { h = fmaxf(hOld[rr] + dt * (dh[rr] + smbr[rr]), 0.0f);
                                   z = ztr[rr] + h; }
            else                 { h = 0.0f; z = zOld[rr]; }
            hN[rr] = h;
            if (r < NYg) {
                sZ[rr + 1][c] = z;
                sHm[rr][c]    = h;
                if (rr == 1) scstoref(EZw + r * W + c, z);   // row r0+1: read by both nbrs
                if (upd) {
                    float t_ma = TMA - LAPSE * z;
                    float t_mj = TMJ - LAPSE * z;
                    float acc  = (t_ma < 0.0f) ? precip[r * W + c] : 0.0f;
                    float abl  = MELTF * fmaxf(t_mj, 0.0f);
                    smbr[rr] = (acc - abl) * mask[r * W + c];
                }
            }
        }
        __syncthreads();   // LDS writeback visible for G

        // ---- G: D(s+1) own staggered rows -> LDS + edge export + max + publish ----
        if (s < NSTEPS - 1) {
            float m = 0.0f;
            #pragma unroll
            for (int rr = 0; rr < 2; ++rr) {
                int i = r0 + rr;
                if (i <= NYg - 2 && c <= NXg - 2) {
                    float d = dfunc(sHm[rr][c], sHm[rr][c + 1],
                                    sHm[rr + 1][c], sHm[rr + 1][c + 1],
                                    sZ[rr + 1][c], sZ[rr + 1][c + 1],
                                    sZ[rr + 2][c], sZ[rr + 2][c + 1]);
                    sD[rr + 1][c] = d;
                    m = fmaxf(m, d);
                    if (rr == 0 && hasA) scstoref(EDw + i * W + c, d);  // row r0 -> above
                    if (rr == 1 && hasB) scstoref(EDw + i * W + c, d);  // row r0+1 -> below
                }
            }
            asm volatile("s_waitcnt vmcnt(0)" ::: "memory");  // exports drained
            #pragma unroll
            for (int off = 32; off >= 1; off >>= 1)
                m = fmaxf(m, __shfl_xor(m, off, 64));
            if (lane == 0) smax16[wid] = m;
            __syncthreads();
            if (c == 0) {
                #pragma unroll
                for (int q = 1; q < 16; ++q) m = fmaxf(m, smax16[q]);
                __hip_atomic_fetch_max(&slots[(s + 1) * SLOT_GROUP + grp * SLOT_STRIDE],
                                       __float_as_uint(m),
                                       __ATOMIC_RELAXED, __HIP_MEMORY_SCOPE_SYSTEM);
                asm volatile("s_waitcnt vmcnt(0)" ::: "memory");  // max visible first
                __hip_atomic_fetch_add(&cnt[grp * 32], 1u,
                                       __ATOMIC_RELAXED, __HIP_MEMORY_SCOPE_SYSTEM);
                __hip_atomic_store(&nbf[b * 32], (unsigned)(s + 1),
                                   __ATOMIC_RELAXED, __HIP_MEMORY_SCOPE_SYSTEM);
            }
        }

        t = nt;
        if (upd) tl = nt;
    }

    // ---- final: H(64) own rows -> d_out ----
    #pragma unroll
    for (int rr = 0; rr < 2; ++rr)
        Hout[(r0 + rr) * W + c] = hN[rr];
}

extern "C" void kernel_launch(void* const* d_in, const int* in_sizes, int n_in,
                              void* d_out, int out_size, void* d_ws, size_t ws_size,
                              hipStream_t stream)
{
    const float* precip = (const float*)d_in[0];
    const float* tma    = (const float*)d_in[1];
    const float* tmj    = (const float*)d_in[2];
    const float* ztopo  = (const float*)d_in[3];
    const float* mask   = (const float*)d_in[4];

    unsigned* ctrl = (unsigned*)d_ws;
    float* g = (float*)d_ws + WS_GRIDS;
    float* EZ0 = g + 0 * GRID_N;
    float* EZ1 = g + 1 * GRID_N;
    float* ED0 = g + 2 * GRID_N;
    float* ED1 = g + 3 * GRID_N;

    k_init<<<dim3(64), dim3(256), 0, stream>>>(ctrl);

    k_run<<<dim3(NB), dim3(1024), 0, stream>>>(EZ0, EZ1, ED0, ED1,
                                               ztopo, precip, mask, tma, tmj,
                                               ctrl, (float*)d_out);
}

// Round 10
// 466.028 us; speedup vs baseline: 1.2420x; 1.2420x over previous
//
#include <hip/hip_runtime.h>
#include <math.h>

#define NYg 1024
#define NXg 1024
#define W   1024
#define NSTEPS 64
#define GRID_N (NYg * W)
#define NB    256                     // block b owns rows 4b..4b+3 (+1 redundant)

// ---- ctrl (dword offsets in d_ws) ----
#define NSLOT 16                      // max-reduction groups (16 blocks each)
#define SLOT_STRIDE 32
#define SLOT_GROUP  (NSLOT * SLOT_STRIDE)     // 512 dwords
#define NSLOTG      (NSTEPS + 1)
#define WS_CNT  (NSLOTG * SLOT_GROUP)         // 16 group counters * 32 dwords
#define WS_NBF  (WS_CNT + NSLOT * 32)         // NB neighbor flags * 32 dwords
#define WS_CTRL_END (WS_NBF + NB * 32)
#define WS_GRIDS 65536                // float offset where exchange arrays begin

constexpr float DXf   = 50.0f;
constexpr float DYf   = 50.0f;
constexpr float TTOTf = 32.0f;
constexpr float DTMAXf= 0.5f;
constexpr float EPSf  = 1e-10f;
constexpr float TFREQ = 5.0f;
constexpr float LAPSE = 0.0065f;
constexpr float MELTF = 0.5f;
constexpr double RHOG = 910.0 * 9.81;
constexpr float  CDf  = (float)(1e-17 * RHOG * RHOG * RHOG);

// memory-side (coherence-point) accessors — bypass non-coherent per-XCD L2s
__device__ __forceinline__ float scloadf(const float* p) {
    return __hip_atomic_load(p, __ATOMIC_RELAXED, __HIP_MEMORY_SCOPE_SYSTEM);
}
__device__ __forceinline__ void scstoref(float* p, float v) {
    __hip_atomic_store(p, v, __ATOMIC_RELAXED, __HIP_MEMORY_SCOPE_SYSTEM);
}
__device__ __forceinline__ unsigned scloadu(const unsigned* p) {
    return __hip_atomic_load(p, __ATOMIC_RELAXED, __HIP_MEMORY_SCOPE_SYSTEM);
}

// backoff poll helper: s_sleep arg must be a compile-time constant
__device__ __forceinline__ void poll_backoff(int& sp) {
    if (sp < 32) { __builtin_amdgcn_s_sleep(1); ++sp; }
    else           __builtin_amdgcn_s_sleep(8);
}

// diffusivity on one staggered cell — expression verbatim from the bit-exact R2 kernel
__device__ __forceinline__ float dfunc(float h00, float h01, float h10, float h11,
                                       float z00, float z01, float z10, float z11)
{
    float havg = 0.25f * (h00 + h11 + h01 + h10);
    float sx = ((z01 - z00) + (z11 - z10)) * (0.5f / DXf);
    float sy = ((z10 - z00) + (z11 - z01)) * (0.5f / DYf);
    float sn = sqrtf(sx * sx + sy * sy + EPSf);
    float h2 = havg * havg;
    float h4 = h2 * h2;
    return CDf * (h4 * havg) * (sn * sn) + EPSf;
}

// ---------------- init: zero ctrl, seed slot group 0 with EPS (D(0)==EPS exactly) ----
__global__ __launch_bounds__(256) void k_init(unsigned* __restrict__ ctrl)
{
    int idx = blockIdx.x * blockDim.x + threadIdx.x;
    int stride = gridDim.x * blockDim.x;
    for (int i = idx; i < WS_CTRL_END; i += stride) {
        unsigned v = 0u;
        if (i < SLOT_GROUP && (i & (SLOT_STRIDE - 1)) == 0) v = __float_as_uint(EPSf);
        ctrl[i] = v;
    }
}

// ---------------- persistent kernel: 256 blocks x 4 rows, short sync chains ----------
__global__ __launch_bounds__(1024, 1) void k_run(
    float* __restrict__ EZ0, float* __restrict__ EZ1,
    float* __restrict__ ED0, float* __restrict__ ED1,
    const float* __restrict__ ztopo, const float* __restrict__ precip,
    const float* __restrict__ mask, const float* __restrict__ tma,
    const float* __restrict__ tmj, unsigned* __restrict__ ctrl,
    float* __restrict__ Hout)
{
    __shared__ float sZ[7][W];    // z rows r0-1 .. r0+5
    __shared__ float sHm[5][W];   // h rows r0 .. r0+4
    __shared__ float sD[6][W];    // staggered D rows r0-1 .. r0+4
    __shared__ unsigned su[NSLOT];
    __shared__ float smax16[16];

    unsigned* slots = ctrl;
    unsigned* cnt   = ctrl + WS_CNT;
    unsigned* nbf   = ctrl + WS_NBF;

    const int c   = threadIdx.x;          // column 0..1023
    const int b   = blockIdx.x;           // owns rows 4b..4b+3 (+1 redundant 4b+4)
    const int r0  = b * 4;
    const int grp = b & (NSLOT - 1);      // 16 blocks per group
    const int lane = c & 63, wid = c >> 6;
    const bool hasA = (b > 0), hasB = (b < NB - 1);

    const float TMA = tma[0], TMJ = tmj[0];

    float smbr[5], ztr[5], hN[5], zN[5];
    float dh[5], hOld[5], zOld[5];
    bool inter[5];

    // C1 stencil for one row (reads LDS only)
    auto c1row = [&](int rr) {
        int r = r0 + rr;
        float zc = 0.0f, hc = 0.0f, d = 0.0f;
        bool iv = false;
        if (r < NYg) {
            zc = sZ[rr + 1][c];
            hc = sHm[rr][c];
            iv = (r >= 1 && r <= NYg - 2 && c >= 1 && c <= NXg - 2);
            if (iv) {
                float zl = sZ[rr + 1][c - 1], zr = sZ[rr + 1][c + 1];
                float zt = sZ[rr][c],         zb = sZ[rr + 2][c];
                float d00 = sD[rr][c - 1],     d01 = sD[rr][c];
                float d10 = sD[rr + 1][c - 1], d11 = sD[rr + 1][c];
                float qxR = -0.5f * (d01 + d11) * (zr - zc) * (1.0f / DXf);
                float qxL = -0.5f * (d00 + d10) * (zc - zl) * (1.0f / DXf);
                float qyB = -0.5f * (d10 + d11) * (zb - zc) * (1.0f / DYf);
                float qyT = -0.5f * (d00 + d01) * (zc - zt) * (1.0f / DYf);
                d = -((qxR - qxL) * (1.0f / DXf) + (qyB - qyT) * (1.0f / DYf));
            }
        }
        dh[rr] = d; hOld[rr] = hc; zOld[rr] = zc; inter[rr] = iv;
    };

    // ---- pre-loop: state(0) into LDS; D(0)=EPS; smb(0), ztopo into registers ----
    #pragma unroll
    for (int q = 0; q < 7; ++q) {
        int r = r0 - 1 + q;
        sZ[q][c] = (r >= 0 && r < NYg) ? ztopo[r * W + c] : 0.0f;
    }
    #pragma unroll
    for (int q = 0; q < 5; ++q) sHm[q][c] = 0.0f;
    #pragma unroll
    for (int q = 0; q < 6; ++q) sD[q][c] = EPSf;
    #pragma unroll
    for (int rr = 0; rr < 5; ++rr) {
        int r = r0 + rr;
        if (r < NYg) {
            float z = ztopo[r * W + c];
            ztr[rr] = z;
            float t_ma = TMA - LAPSE * z;
            float t_mj = TMJ - LAPSE * z;
            float acc  = (t_ma < 0.0f) ? precip[r * W + c] : 0.0f;
            float abl  = MELTF * fmaxf(t_mj, 0.0f);
            smbr[rr] = (acc - abl) * mask[r * W + c];
        } else { ztr[rr] = 0.0f; smbr[rr] = 0.0f; }
    }
    __syncthreads();

    float t = 0.0f, tl = 0.0f;

    for (int s = 0; s < NSTEPS; ++s) {
        const float* EZr = (s & 1) ? EZ1 : EZ0;
        float*       EZw = (s & 1) ? EZ0 : EZ1;
        const float* EDr = (s & 1) ? ED1 : ED0;
        float*       EDw = (s & 1) ? ED0 : ED1;

        // ---- A: neighbor wait, issue halo loads, hide latency behind interior C1 ----
        if (s > 0) {
            if (c == 0 && hasA) {
                int sp = 0;
                while (scloadu(&nbf[(b - 1) * 32]) < (unsigned)s) poll_backoff(sp);
            }
            if (c == 64 && hasB) {
                int sp = 0;
                while (scloadu(&nbf[(b + 1) * 32]) < (unsigned)s) poll_backoff(sp);
            }
            __syncthreads();
            float zA = 0.0f, zB = 0.0f, dA = 0.0f, dB = 0.0f;
            if (hasA) { zA = scloadf(EZr + (r0 - 1) * W + c);
                        if (c <= NXg - 2) dA = scloadf(EDr + (r0 - 1) * W + c); }
            if (hasB) { zB = scloadf(EZr + (r0 + 5) * W + c);
                        if (c <= NXg - 2) dB = scloadf(EDr + (r0 + 4) * W + c); }
            // interior rows: no halo dependence — overlaps the loads above
            c1row(1); c1row(2); c1row(3);
            if (hasA) { sZ[0][c] = zA; if (c <= NXg - 2) sD[0][c] = dA; }
            if (hasB) { sZ[6][c] = zB; if (c <= NXg - 2) sD[5][c] = dB; }
            __syncthreads();
            c1row(0); c1row(4);
        } else {
            c1row(0); c1row(1); c1row(2); c1row(3); c1row(4);
        }

        // ---- W: global dt wait (monotone counters; 16 per group) ----
        if (c < NSLOT) {
            unsigned tgt = 16u * (unsigned)s;
            int sp = 0;
            while (scloadu(&cnt[c * 32]) < tgt) poll_backoff(sp);
            su[c] = scloadu(&slots[s * SLOT_GROUP + c * SLOT_STRIDE]);
        }
        __syncthreads();   // also: all C1 LDS reads complete before E writes

        unsigned mb = su[0];
        #pragma unroll
        for (int q = 1; q < NSLOT; ++q) mb = max(mb, su[q]);
        float mD = __uint_as_float(mb);
        float dt = fminf(2500.0f / (2.7f * mD), DTMAXf);
        if (!(t < TTOTf)) dt = 0.0f;
        float nt  = t + dt;
        bool  upd = (nt - tl) >= TFREQ;

        // ---- C2: finalize h/z into registers; E: LDS writeback (no exports yet) ----
        #pragma unroll
        for (int rr = 0; rr < 5; ++rr) {
            int r = r0 + rr;
            float h, z;
            if (r >= NYg)        { h = 0.0f; z = 0.0f; }
            else if (inter[rr])  { h = fmaxf(hOld[rr] + dt * (dh[rr] + smbr[rr]), 0.0f);
                                   z = ztr[rr] + h; }
            else                 { h = 0.0f; z = zOld[rr]; }
            hN[rr] = h; zN[rr] = z;
            if (r < NYg) { sZ[rr + 1][c] = z; sHm[rr][c] = h; }
        }
        __syncthreads();   // new state visible for G

        // ---- G: D(s+1) -> LDS + max; publish dt path FIRST, then exports, then nbf ----
        if (s < NSTEPS - 1) {
            float m = 0.0f, d0 = 0.0f, d3 = 0.0f;
            #pragma unroll
            for (int rr = 0; rr < 4; ++rr) {
                int i = r0 + rr;
                if (i <= NYg - 2 && c <= NXg - 2) {
                    float d = dfunc(sHm[rr][c], sHm[rr][c + 1],
                                    sHm[rr + 1][c], sHm[rr + 1][c + 1],
                                    sZ[rr + 1][c], sZ[rr + 1][c + 1],
                                    sZ[rr + 2][c], sZ[rr + 2][c + 1]);
                    sD[rr + 1][c] = d;
                    m = fmaxf(m, d);
                    if (rr == 0) d0 = d;
                    if (rr == 3) d3 = d;
                }
            }
            #pragma unroll
            for (int off = 32; off >= 1; off >>= 1)
                m = fmaxf(m, __shfl_xor(m, off, 64));
            if (lane == 0) smax16[wid] = m;
            __syncthreads();
            if (c == 0) {
                #pragma unroll
                for (int q = 1; q < 16; ++q) m = fmaxf(m, smax16[q]);
                __hip_atomic_fetch_max(&slots[(s + 1) * SLOT_GROUP + grp * SLOT_STRIDE],
                                       __float_as_uint(m),
                                       __ATOMIC_RELAXED, __HIP_MEMORY_SCOPE_SYSTEM);
                asm volatile("s_waitcnt vmcnt(0)" ::: "memory");  // max lands before cnt
                __hip_atomic_fetch_add(&cnt[grp * 32], 1u,
                                       __ATOMIC_RELAXED, __HIP_MEMORY_SCOPE_SYSTEM);
            }
            // halo exports (neighbor path — off the global dt chain)
            if (hasA) {
                scstoref(EZw + (r0 + 1) * W + c, zN[1]);
                if (c <= NXg - 2 && r0 <= NYg - 2) scstoref(EDw + r0 * W + c, d0);
            }
            if (hasB) {
                scstoref(EZw + (r0 + 3) * W + c, zN[3]);
                if (c <= NXg - 2 && r0 + 3 <= NYg - 2) scstoref(EDw + (r0 + 3) * W + c, d3);
            }
            asm volatile("s_waitcnt vmcnt(0)" ::: "memory");  // exports drained (per wave)
            __syncthreads();                                   // all waves drained
            if (c == 0)
                __hip_atomic_store(&nbf[b * 32], (unsigned)(s + 1),
                                   __ATOMIC_RELAXED, __HIP_MEMORY_SCOPE_SYSTEM);

            // smb refresh — feeds next step only, so keep off the critical path
            if (upd) {
                #pragma unroll
                for (int rr = 0; rr < 5; ++rr) {
                    int r = r0 + rr;
                    if (r < NYg) {
                        float z = zN[rr];
                        float t_ma = TMA - LAPSE * z;
                        float t_mj = TMJ - LAPSE * z;
                        float acc  = (t_ma < 0.0f) ? precip[r * W + c] : 0.0f;
                        float abl  = MELTF * fmaxf(t_mj, 0.0f);
                        smbr[rr] = (acc - abl) * mask[r * W + c];
                    }
                }
            }
        }

        t = nt;
        if (upd) tl = nt;
    }

    // ---- final: H(64) own rows -> d_out ----
    #pragma unroll
    for (int rr = 0; rr < 4; ++rr)
        Hout[(r0 + rr) * W + c] = hN[rr];
}

extern "C" void kernel_launch(void* const* d_in, const int* in_sizes, int n_in,
                              void* d_out, int out_size, void* d_ws, size_t ws_size,
                              hipStream_t stream)
{
    const float* precip = (const float*)d_in[0];
    const float* tma    = (const float*)d_in[1];
    const float* tmj    = (const float*)d_in[2];
    const float* ztopo  = (const float*)d_in[3];
    const float* mask   = (const float*)d_in[4];

    unsigned* ctrl = (unsigned*)d_ws;
    float* g = (float*)d_ws + WS_GRIDS;
    float* EZ0 = g + 0 * GRID_N;
    float* EZ1 = g + 1 * GRID_N;
    float* ED0 = g + 2 * GRID_N;
    float* ED1 = g + 3 * GRID_N;

    k_init<<<dim3(64), dim3(256), 0, stream>>>(ctrl);

    k_run<<<dim3(NB), dim3(1024), 0, stream>>>(EZ0, EZ1, ED0, ED1,
                                               ztopo, precip, mask, tma, tmj,
                                               ctrl, (float*)d_out);
}